// Round 5
// baseline (1478.307 us; speedup 1.0000x reference)
//
#include <hip/hip_runtime.h>
#include <math.h>

#define BB 64
#define LL 160
#define DD 768
#define HH 4
#define NVV 197
#define SS 159

typedef unsigned short u16;
typedef __attribute__((ext_vector_type(8))) short bf16x8;
typedef __attribute__((ext_vector_type(4))) float f32x4;

union QU { uint4 u; bf16x8 v; };

__device__ __forceinline__ u16 f2bf(float a) {
  unsigned u = __builtin_bit_cast(unsigned, a);
  u = (u + 0x7FFFu + ((u >> 16) & 1u)) >> 16;
  return (u16)u;
}
__device__ __forceinline__ unsigned f2bf2(float a, float b) {
  return (unsigned)f2bf(a) | ((unsigned)f2bf(b) << 16);
}
__device__ __forceinline__ float bf2f(u16 h) {
  unsigned u = ((unsigned)h) << 16;
  return __builtin_bit_cast(float, u);
}
__device__ __forceinline__ float to_f(float x) { return x; }
__device__ __forceinline__ float to_f(u16 x) { return bf2f(x); }

__device__ __forceinline__ void async16(const u16* g, void* l) {
  __builtin_amdgcn_global_load_lds(
      (const __attribute__((address_space(1))) void*)g,
      (__attribute__((address_space(3))) void*)l, 16, 0, 0);
}

// load 8 bf16 from a row (vector fast path when aligned & in-bounds)
__device__ __forceinline__ uint4 load_bf8(const u16* __restrict__ P, long long rowbase,
                                          int valid, int kb, int K) {
  uint4 r;
  if (valid && (kb + 8 <= K) && (((rowbase + kb) & 7) == 0)) {
    r = *(const uint4*)(P + rowbase + kb);
  } else {
    u16 e[8];
    #pragma unroll
    for (int i = 0; i < 8; ++i) { int k = kb + i; e[i] = (valid && k < K) ? P[rowbase + k] : (u16)0; }
    r.x = e[0] | ((unsigned)e[1] << 16); r.y = e[2] | ((unsigned)e[3] << 16);
    r.z = e[4] | ((unsigned)e[5] << 16); r.w = e[6] | ((unsigned)e[7] << 16);
  }
  return r;
}

// load 8 f32 from a row -> packed bf16 (for sim kernel)
__device__ __forceinline__ uint4 load_row8(const float* __restrict__ P, long long rowbase,
                                           int valid_row, int kb, int K) {
  float f[8];
  if (valid_row && (kb + 8 <= K)) {
    const float4* p0 = (const float4*)(P + rowbase + kb);
    float4 x = p0[0], y = p0[1];
    f[0] = x.x; f[1] = x.y; f[2] = x.z; f[3] = x.w;
    f[4] = y.x; f[5] = y.y; f[6] = y.z; f[7] = y.w;
  } else {
    #pragma unroll
    for (int e = 0; e < 8; ++e) { int k = kb + e; f[e] = (valid_row && k < K) ? P[rowbase + k] : 0.f; }
  }
  uint4 r;
  r.x = f2bf2(f[0], f[1]); r.y = f2bf2(f[2], f[3]);
  r.z = f2bf2(f[4], f[5]); r.w = f2bf2(f[6], f[7]);
  return r;
}

// ---------------- 128x128 MFMA GEMM (TRANSB only), global_load_lds staging ----------------
// C = alpha * A @ B^T (+bias) (+residB) (+=Cf if accum) (/rowdiv) (relu)
__global__ __launch_bounds__(256) void gemm128(
    const u16* __restrict__ A, const u16* __restrict__ Bm,
    float* __restrict__ Cf, u16* __restrict__ Cb,
    int M, int N, int K, int lda, int ldb, int ldc,
    float alpha, const float* __restrict__ bias, const u16* __restrict__ residB,
    const float* __restrict__ rowdiv, int relu, int accum) {
  __shared__ uint4 As[4][128];  // [kg][row] : 8 bf16 at k = k0+kg*8
  __shared__ uint4 Bs[4][128];

  int t = threadIdx.x;
  int l = t & 63, w = t >> 6;
  int row0 = blockIdx.y * 128, col0 = blockIdx.x * 128;
  int wr = (w >> 1) * 64, wc = (w & 1) * 64;

  f32x4 acc[4][4] = {};

  for (int k0 = 0; k0 < K; k0 += 32) {
    // wave w stages kg = w: rows i*64+l of A and B tiles (linear lane->slot)
    #pragma unroll
    for (int i = 0; i < 2; ++i) {
      int r = i * 64 + l;
      int ga = row0 + r;
      if (ga < M) async16(A + (long long)ga * lda + k0 + w * 8, &As[w][i * 64]);
      int gb = col0 + r;
      if (gb < N) async16(Bm + (long long)gb * ldb + k0 + w * 8, &Bs[w][i * 64]);
    }
    __syncthreads();
    int kg = l >> 4, li = l & 15;
    QU a[4], b[4];
    #pragma unroll
    for (int i = 0; i < 4; ++i) a[i].u = As[kg][wr + i * 16 + li];
    #pragma unroll
    for (int j = 0; j < 4; ++j) b[j].u = Bs[kg][wc + j * 16 + li];
    #pragma unroll
    for (int i = 0; i < 4; ++i)
      #pragma unroll
      for (int j = 0; j < 4; ++j)
        acc[i][j] = __builtin_amdgcn_mfma_f32_16x16x32_bf16(a[i].v, b[j].v, acc[i][j], 0, 0, 0);
    __syncthreads();
  }

  #pragma unroll
  for (int i = 0; i < 4; ++i) {
    #pragma unroll
    for (int j = 0; j < 4; ++j) {
      int colj = col0 + wc + j * 16 + (l & 15);
      float bv = (bias && colj < N) ? bias[colj] : 0.f;
      #pragma unroll
      for (int r = 0; r < 4; ++r) {
        int gr = row0 + wr + i * 16 + (l >> 4) * 4 + r;
        if (gr < M && colj < N) {
          long long ci = (long long)gr * ldc + colj;
          float v = acc[i][j][r] * alpha + bv;
          if (residB) v += bf2f(residB[ci]);
          if (accum) v += Cf[ci];
          if (rowdiv) v /= rowdiv[gr];
          if (relu) v = fmaxf(v, 0.f);
          if (Cf) Cf[ci] = v;
          if (Cb) Cb[ci] = f2bf(v);
        }
      }
    }
  }
}

// ---------------- bf16-input MFMA GEMM, 64x64 tile, BK=32 (batched, small shapes) ----------------
template<bool TRANSB>
__global__ __launch_bounds__(256) void gemm_bf16(
    const u16* __restrict__ A, const u16* __restrict__ Bm,
    float* __restrict__ Cf, u16* __restrict__ Cb,
    int M, int N, int K, int lda, int ldb, int ldc,
    long long sAb, long long sBb, long long sCb,
    float alpha, const float* __restrict__ bias, const u16* __restrict__ residB,
    const float* __restrict__ rowdiv, int relu, int accum) {
  int bb = blockIdx.z;
  A += bb * sAb;
  Bm += bb * sBb;
  long long coff = bb * sCb;

  __shared__ uint4 As4[4][64];
  __shared__ uint4 Bs4[4][64];

  int row0 = blockIdx.y * 64, col0 = blockIdx.x * 64;
  int t = threadIdx.x;
  int l = t & 63, w = t >> 6;
  int mq = (w >> 1) * 32, nq = (w & 1) * 32;

  int am = t >> 2, akq = t & 3;
  int bn = t & 63, bkq = t >> 6;

  f32x4 acc[2][2] = {};

  for (int k0 = 0; k0 < K; k0 += 32) {
    As4[akq][am] = load_bf8(A, (long long)(row0 + am) * lda, (row0 + am) < M, k0 + akq * 8, K);
    if (TRANSB) {
      Bs4[akq][am] = load_bf8(Bm, (long long)(col0 + am) * ldb, (col0 + am) < N, k0 + akq * 8, K);
    } else {
      int gn = col0 + bn;
      u16 e[8];
      #pragma unroll
      for (int i = 0; i < 8; ++i) {
        int k = k0 + bkq * 8 + i;
        e[i] = (gn < N && k < K) ? Bm[(long long)k * ldb + gn] : (u16)0;
      }
      uint4 r;
      r.x = e[0] | ((unsigned)e[1] << 16); r.y = e[2] | ((unsigned)e[3] << 16);
      r.z = e[4] | ((unsigned)e[5] << 16); r.w = e[6] | ((unsigned)e[7] << 16);
      Bs4[bkq][bn] = r;
    }
    __syncthreads();
    int kg = l >> 4, li = l & 15;
    QU a0, a1, b0, b1;
    a0.u = As4[kg][mq + li];
    a1.u = As4[kg][mq + 16 + li];
    b0.u = Bs4[kg][nq + li];
    b1.u = Bs4[kg][nq + 16 + li];
    acc[0][0] = __builtin_amdgcn_mfma_f32_16x16x32_bf16(a0.v, b0.v, acc[0][0], 0, 0, 0);
    acc[0][1] = __builtin_amdgcn_mfma_f32_16x16x32_bf16(a0.v, b1.v, acc[0][1], 0, 0, 0);
    acc[1][0] = __builtin_amdgcn_mfma_f32_16x16x32_bf16(a1.v, b0.v, acc[1][0], 0, 0, 0);
    acc[1][1] = __builtin_amdgcn_mfma_f32_16x16x32_bf16(a1.v, b1.v, acc[1][1], 0, 0, 0);
    __syncthreads();
  }

  #pragma unroll
  for (int i = 0; i < 2; ++i) {
    #pragma unroll
    for (int j = 0; j < 2; ++j) {
      int colj = col0 + nq + j * 16 + (l & 15);
      float bv = (bias && colj < N) ? bias[colj] : 0.f;
      #pragma unroll
      for (int r = 0; r < 4; ++r) {
        int gr = row0 + mq + i * 16 + (l >> 4) * 4 + r;
        if (gr < M && colj < N) {
          long long ci = coff + (long long)gr * ldc + colj;
          float v = acc[i][j][r] * alpha + bv;
          if (residB) v += bf2f(residB[ci]);
          if (accum) v += Cf[ci];
          if (rowdiv) v /= rowdiv[gr];
          if (relu) v = fmaxf(v, 0.f);
          if (Cf) Cf[ci] = v;
          if (Cb) Cb[ci] = f2bf(v);
        }
      }
    }
  }
}

// ---------------- sim GEMM (f32 in) fused with cosine*adj epilogue -> adj_ti bf16 ----------------
__global__ __launch_bounds__(256) void sim_kernel(
    const float* __restrict__ TII, const float* __restrict__ nrm,
    const float* __restrict__ adjf, u16* __restrict__ adjtiB) {
  int bb = blockIdx.z;
  const float* T = TII + (long long)bb * LL * DD;

  __shared__ uint4 As4[4][64];
  __shared__ uint4 Bs4[4][64];

  int row0 = blockIdx.y * 64, col0 = blockIdx.x * 64;
  int t = threadIdx.x;
  int l = t & 63, w = t >> 6;
  int mq = (w >> 1) * 32, nq = (w & 1) * 32;
  int am = t >> 2, akq = t & 3;

  f32x4 acc[2][2] = {};

  for (int k0 = 0; k0 < DD; k0 += 32) {
    As4[akq][am] = load_row8(T, (long long)(row0 + am) * DD, (row0 + am) < LL, k0 + akq * 8, DD);
    Bs4[akq][am] = load_row8(T, (long long)(col0 + am) * DD, (col0 + am) < LL, k0 + akq * 8, DD);
    __syncthreads();
    int kg = l >> 4, li = l & 15;
    QU a0, a1, b0, b1;
    a0.u = As4[kg][mq + li];
    a1.u = As4[kg][mq + 16 + li];
    b0.u = Bs4[kg][nq + li];
    b1.u = Bs4[kg][nq + 16 + li];
    acc[0][0] = __builtin_amdgcn_mfma_f32_16x16x32_bf16(a0.v, b0.v, acc[0][0], 0, 0, 0);
    acc[0][1] = __builtin_amdgcn_mfma_f32_16x16x32_bf16(a0.v, b1.v, acc[0][1], 0, 0, 0);
    acc[1][0] = __builtin_amdgcn_mfma_f32_16x16x32_bf16(a1.v, b0.v, acc[1][0], 0, 0, 0);
    acc[1][1] = __builtin_amdgcn_mfma_f32_16x16x32_bf16(a1.v, b1.v, acc[1][1], 0, 0, 0);
    __syncthreads();
  }

  #pragma unroll
  for (int i = 0; i < 2; ++i) {
    #pragma unroll
    for (int j = 0; j < 2; ++j) {
      int colj = col0 + nq + j * 16 + (l & 15);
      #pragma unroll
      for (int r = 0; r < 4; ++r) {
        int gr = row0 + mq + i * 16 + (l >> 4) * 4 + r;
        if (gr < LL && colj < LL) {
          float nl = nrm[bb * LL + gr], nm = nrm[bb * LL + colj];
          long long ai = ((long long)bb * LL + gr) * LL + colj;
          float s = acc[i][j][r] / fmaxf(nl * nm, 1e-16f);
          adjtiB[ai] = f2bf(adjf[ai] * s);
        }
      }
    }
  }
}

// ---------------- block reduce ----------------
__device__ __forceinline__ float block_sum(float v, float* sm) {
  #pragma unroll
  for (int o = 32; o > 0; o >>= 1) v += __shfl_down(v, o);
  int lane = threadIdx.x & 63, w = threadIdx.x >> 6;
  if (lane == 0) sm[w] = v;
  __syncthreads();
  if (threadIdx.x == 0) sm[0] = sm[0] + sm[1] + sm[2] + sm[3];
  __syncthreads();
  float r = sm[0];
  __syncthreads();
  return r;
}

// ---------------- LayerNorm: optional f32 out, bf16 out, row-norm out ----------------
__global__ __launch_bounds__(256) void ln_kernel(const float* __restrict__ x, float* __restrict__ yf,
                                                 u16* __restrict__ yb,
                                                 const float* __restrict__ g, const float* __restrict__ b,
                                                 float* __restrict__ nrmout) {
  __shared__ float sm[4];
  long long row = blockIdx.x;
  const float* xr = x + row * DD;
  int t = threadIdx.x;
  float v0 = xr[t], v1 = xr[t + 256], v2 = xr[t + 512];
  float s = block_sum(v0 + v1 + v2, sm);
  float m = s * (1.f / 768.f);
  float d0 = v0 - m, d1 = v1 - m, d2 = v2 - m;
  float vv = block_sum(d0 * d0 + d1 * d1 + d2 * d2, sm);
  float rstd = rsqrtf(vv * (1.f / 768.f) + 1e-5f);
  float y0 = d0 * rstd * g[t] + b[t];
  float y1 = d1 * rstd * g[t + 256] + b[t + 256];
  float y2 = d2 * rstd * g[t + 512] + b[t + 512];
  if (yf) { float* yr = yf + row * DD; yr[t] = y0; yr[t + 256] = y1; yr[t + 512] = y2; }
  if (yb) { u16* yr = yb + row * DD; yr[t] = f2bf(y0); yr[t + 256] = f2bf(y1); yr[t + 512] = f2bf(y2); }
  if (nrmout) {
    float s2 = block_sum(y0 * y0 + y1 * y1 + y2 * y2, sm);
    if (t == 0) nrmout[row] = sqrtf(s2);
  }
}

// ---------------- softmax f32 in -> bf16 out (ld 200) ----------------
__global__ __launch_bounds__(256) void softmax_kernel(const float* __restrict__ S, u16* __restrict__ PB,
                                                      int nrows) {
  int row = blockIdx.x * 4 + (threadIdx.x >> 6);
  int lane = threadIdx.x & 63;
  if (row >= nrows) return;
  const float* ar = S + (long long)row * NVV;
  u16* pr = PB + (long long)row * 200;
  float vals[4];
  float mx = -1e30f;
  int cnt = 0;
  for (int i = lane; i < NVV; i += 64) { float v = ar[i]; vals[cnt++] = v; mx = fmaxf(mx, v); }
  #pragma unroll
  for (int o = 32; o > 0; o >>= 1) mx = fmaxf(mx, __shfl_xor(mx, o));
  float sum = 0.f;
  for (int j = 0; j < cnt; ++j) { vals[j] = __expf(vals[j] - mx); sum += vals[j]; }
  #pragma unroll
  for (int o = 32; o > 0; o >>= 1) sum += __shfl_xor(sum, o);
  float inv = 1.f / sum;
  cnt = 0;
  for (int i = lane; i < NVV; i += 64) pr[i] = f2bf(vals[cnt++] * inv);
  for (int i = NVV + lane; i < 200; i += 64) pr[i] = 0;
}

// ---------------- direct span-sum pool: src (B,L,D) -> dst bf16 (B,L,D) ----------------
template<typename T>
__global__ __launch_bounds__(256) void pool_kernel(const T* __restrict__ src, u16* __restrict__ dst,
                                                   const int* __restrict__ wl, const int* __restrict__ tran) {
  int b = blockIdx.x, i = blockIdx.y, d = threadIdx.x;
  long long ob = ((long long)b * LL + i) * DD;
  float r0 = 0.f, r1 = 0.f, r2 = 0.f;
  if (i > 0 && (i - 1) < wl[b]) {
    int w = i - 1;
    int st = tran[(b * SS + w) * 2];
    int en = tran[(b * SS + w) * 2 + 1];
    const T* sb = src + (long long)b * LL * DD;
    for (int s = st; s < en; ++s) {
      const T* rp = sb + (long long)(1 + s) * DD;
      r0 += to_f(rp[d]); r1 += to_f(rp[d + 256]); r2 += to_f(rp[d + 512]);
    }
  }
  dst[ob + d] = f2bf(r0);
  dst[ob + d + 256] = f2bf(r1);
  dst[ob + d + 512] = f2bf(r2);
}

// ---------------- den / den_ti ----------------
__global__ __launch_bounds__(256) void den_kernel(const float* __restrict__ adjf, const u16* __restrict__ atB,
                                                  float* __restrict__ den, float* __restrict__ den_ti) {
  __shared__ float sm[4];
  int bl = blockIdx.x, m = threadIdx.x;
  float a = 0.f, at = 0.f;
  if (m < LL) {
    long long idx = (long long)bl * LL + m;
    a = adjf[idx];
    at = bf2f(atB[idx]);
  }
  float sa = block_sum(a, sm);
  float sat = block_sum(at, sm);
  if (m == 0) { den[bl] = sa + 1.f; den_ti[bl] = sat + 1.f; }
}

// ---------------- masked mean (bf16 in, bf16 out into local_in) ----------------
__global__ __launch_bounds__(256) void gcn_kernel(const u16* __restrict__ g, const float* __restrict__ mask,
                                                  u16* __restrict__ outB, int coloff) {
  int b = blockIdx.x;
  int d = blockIdx.y * 256 + threadIdx.x;
  float s = 0.f, wn = 0.f;
  for (int l = 0; l < LL; ++l) {
    float mk = mask[b * LL + l];
    wn += mk;
    s += mk * bf2f(g[((long long)b * LL + l) * DD + d]);
  }
  outB[(long long)b * (2 * DD) + coloff + d] = f2bf(s / wn);
}

// ---------------- final ----------------
__global__ __launch_bounds__(256) void final_kernel(const float* __restrict__ gb, const float* __restrict__ lf,
                                                    const float* __restrict__ ow, const float* __restrict__ ob,
                                                    float* __restrict__ out) {
  __shared__ float sm[4];
  int b = blockIdx.x / 3, c = blockIdx.x % 3;
  int t = threadIdx.x;
  float s = 0.f;
  for (int k = t; k < DD; k += 256) {
    s += gb[b * DD + k] * ow[k * 3 + c];
    s += lf[b * DD + k] * ow[(DD + k) * 3 + c];
  }
  float tot = block_sum(s, sm);
  if (t == 0) out[b * 3 + c] = tot + ob[c];
}

// ---------------- f32 -> bf16 elementwise (n multiple of 4) ----------------
__global__ __launch_bounds__(256) void conv_kernel(const float4* __restrict__ x, uint2* __restrict__ y, int n4) {
  int i = blockIdx.x * 256 + threadIdx.x;
  if (i < n4) {
    float4 v = x[i];
    uint2 o;
    o.x = f2bf2(v.x, v.y);
    o.y = f2bf2(v.z, v.w);
    y[i] = o;
  }
}

// ---------------- transpose-convert: dst[c][r] = src[r*lds + c], bf16 out ----------------
__global__ __launch_bounds__(256) void tconv_kernel(const float* __restrict__ src, u16* __restrict__ dst,
                                                    int R, int C, int lds, int ldd) {
  __shared__ float sm[32][33];
  int t = threadIdx.x;
  int tx = t & 31, ty8 = t >> 5;
  int r0 = blockIdx.y * 32, c0 = blockIdx.x * 32;
  for (int i = ty8; i < 32; i += 8) {
    int r = r0 + i, c = c0 + tx;
    sm[i][tx] = (r < R && c < C) ? src[(long long)r * lds + c] : 0.f;
  }
  __syncthreads();
  for (int i = ty8; i < 32; i += 8) {
    int c = c0 + i, r = r0 + tx;
    if (c < C && r < R) dst[(long long)c * ldd + r] = f2bf(sm[tx][i]);
  }
}

// ---------------- host wrappers ----------------
static void gemm(hipStream_t s, bool transb, const u16* A, const u16* B, float* Cf, u16* Cb,
                 int M, int N, int K, int lda, int ldb, int ldc, int batches,
                 long long sAb, long long sBb, long long sCb, float alpha,
                 const float* bias, const u16* residB, const float* rowdiv, int relu, int accum) {
  dim3 g((N + 63) / 64, (M + 63) / 64, batches);
  if (transb)
    gemm_bf16<true><<<g, 256, 0, s>>>(A, B, Cf, Cb, M, N, K, lda, ldb, ldc, sAb, sBb, sCb,
                                      alpha, bias, residB, rowdiv, relu, accum);
  else
    gemm_bf16<false><<<g, 256, 0, s>>>(A, B, Cf, Cb, M, N, K, lda, ldb, ldc, sAb, sBb, sCb,
                                       alpha, bias, residB, rowdiv, relu, accum);
}

static void gemm128h(hipStream_t s, const u16* A, const u16* B, float* Cf, u16* Cb,
                     int M, int N, int K, int lda, int ldb, int ldc, float alpha,
                     const float* bias, const u16* residB, const float* rowdiv,
                     int relu, int accum) {
  dim3 g((N + 127) / 128, (M + 127) / 128, 1);
  gemm128<<<g, 256, 0, s>>>(A, B, Cf, Cb, M, N, K, lda, ldb, ldc,
                            alpha, bias, residB, rowdiv, relu, accum);
}

extern "C" void kernel_launch(void* const* d_in, const int* in_sizes, int n_in,
                              void* d_out, int out_size, void* d_ws, size_t ws_size,
                              hipStream_t stream) {
  const float* text_hidden = (const float*)d_in[0];
  const float* vit_feature = (const float*)d_in[1];
  const float* pooler_out = (const float*)d_in[2];
  const float* target_mask = (const float*)d_in[3];
  const float* adj = (const float*)d_in[4];
  const float* ln_g = (const float*)d_in[5];
  const float* ln_b = (const float*)d_in[6];
  const float* wq = (const float*)d_in[7];
  const float* wk = (const float*)d_in[8];
  const float* wv = (const float*)d_in[9];
  const float* fc_w = (const float*)d_in[10];
  const float* mha_ln_g = (const float*)d_in[11];
  const float* mha_ln_b = (const float*)d_in[12];
  const float* w1b = (const float*)d_in[15];
  const float* b1b = (const float*)d_in[16];
  const float* w2b = (const float*)d_in[19];
  const float* b2b = (const float*)d_in[20];
  const float* loc_w = (const float*)d_in[21];
  const float* loc_b = (const float*)d_in[22];
  const float* out_w = (const float*)d_in[23];
  const float* out_b = (const float*)d_in[24];
  const int* word_length = (const int*)d_in[25];
  const int* tran = (const int*)d_in[26];
  float* out = (float*)d_out;

  const long long BLD = (long long)BB * LL * DD;   // 7,864,320
  const long long BND = (long long)BB * NVV * DD;  // 9,682,944

  char* base = (char*)d_ws;
  auto alloc = [&](size_t bytes) { char* p = base; base += (bytes + 255) & ~(size_t)255; return p; };

  float* R_ACC = (float*)alloc(BLD * 4);                 // tii_pre -> tii (f32)
  float* R_S   = (float*)alloc((size_t)BB * LL * NVV * 4); // attention scores
  u16* TFB   = (u16*)alloc(BLD * 2);                     // text_feat bf16 -> h2B
  u16* vitB  = (u16*)alloc(BND * 2);                     // vit bf16 -> tmpsB -> g1B
  u16* X1    = (u16*)alloc(BLD * 2);                     // qB -> ctxB -> tmpsTiB -> g2B
  u16* X2    = (u16*)alloc(BND * 2);                     // kB/vB -> h1B
  u16* PB    = (u16*)alloc((size_t)BB * LL * 200 * 2);   // softmax probs (ld 200)
  u16* adjB  = (u16*)alloc((size_t)BB * LL * LL * 2);
  u16* adjtiB= (u16*)alloc((size_t)BB * LL * LL * 2);
  u16* W0 = (u16*)alloc((size_t)768 * 768 * 2);          // wq_h^T
  u16* W1 = (u16*)alloc((size_t)768 * 768 * 2);          // wk_h^T
  u16* W2 = (u16*)alloc((size_t)768 * 768 * 2);          // wv_h^T
  u16* W3 = (u16*)alloc((size_t)768 * 768 * 2);          // fc_h^T
  u16* w1bT = (u16*)alloc((size_t)768 * 768 * 2);
  u16* w2bT = (u16*)alloc((size_t)768 * 768 * 2);
  u16* locT = (u16*)alloc((size_t)768 * 1536 * 2);
  u16* linB = (u16*)alloc((size_t)BB * 1536 * 2);
  float* nrm = (float*)alloc((size_t)BB * LL * 4);
  float* den = (float*)alloc((size_t)BB * LL * 4);
  float* den_ti = (float*)alloc((size_t)BB * LL * 4);
  float* global_bert = (float*)alloc((size_t)BB * DD * 4);
  float* local_feat = (float*)alloc((size_t)BB * DD * 4);
  u16* tmpsB = vitB;
  u16* tmpsTiB = X1;
  u16* h1B = X2;
  u16* h2B = TFB;
  u16* g1B = vitB;
  u16* g2B = X1;

  const float inv_sqrt_d = 1.0f / sqrtf((float)DD);
  const long long sA_L = (long long)LL * DD;
  const long long sB_NV = (long long)NVV * DD;

  // one-time conversions
  {
    int n4 = (int)(BND / 4);
    conv_kernel<<<(n4 + 255) / 256, 256, 0, stream>>>((const float4*)vit_feature, (uint2*)vitB, n4);
    int n4a = (int)((long long)BB * LL * LL / 4);
    conv_kernel<<<(n4a + 255) / 256, 256, 0, stream>>>((const float4*)adj, (uint2*)adjB, n4a);
    tconv_kernel<<<dim3(24, 24), 256, 0, stream>>>(w1b, w1bT, 768, 768, 768, 768);
    tconv_kernel<<<dim3(24, 24), 256, 0, stream>>>(w2b, w2bT, 768, 768, 768, 768);
    tconv_kernel<<<dim3(24, 48), 256, 0, stream>>>(loc_w, locT, 1536, 768, 768, 1536);
  }

  // 1. text_feat = LN(text_hidden) -> bf16
  ln_kernel<<<BB * LL, 256, 0, stream>>>(text_hidden, nullptr, TFB, ln_g, ln_b, nullptr);

  // 2. per-head attention, accumulating pre-LN tii (f32)
  for (int h = 0; h < HH; ++h) {
    tconv_kernel<<<dim3(24, 24), 256, 0, stream>>>(wq + h * 768, W0, 768, 768, 3072, 768);
    tconv_kernel<<<dim3(24, 24), 256, 0, stream>>>(wk + h * 768, W1, 768, 768, 3072, 768);
    tconv_kernel<<<dim3(24, 24), 256, 0, stream>>>(wv + h * 768, W2, 768, 768, 3072, 768);
    tconv_kernel<<<dim3(24, 24), 256, 0, stream>>>(fc_w + (long long)h * 768 * 768, W3, 768, 768, 768, 768);
    // qB = TFB @ W0^T   (flat 128x128 path)
    gemm128h(stream, TFB, W0, nullptr, X1, BB * LL, DD, DD, DD, DD, DD,
             1.f, nullptr, nullptr, nullptr, 0, 0);
    // kB = vitB @ W1^T
    gemm128h(stream, vitB, W1, nullptr, X2, BB * NVV, DD, DD, DD, DD, DD,
             1.f, nullptr, nullptr, nullptr, 0, 0);
    // S = qB @ kB^T / sqrt(D)   (batched 64x64)
    gemm(stream, true, X1, X2, R_S, nullptr, LL, NVV, DD, DD, DD, NVV,
         BB, sA_L, sB_NV, (long long)LL * NVV, inv_sqrt_d, nullptr, nullptr, nullptr, 0, 0);
    // P = softmax(S) -> bf16 ld 200
    softmax_kernel<<<(BB * LL + 3) / 4, 256, 0, stream>>>(R_S, PB, BB * LL);
    // vB = vitB @ W2^T (overwrite kB)
    gemm128h(stream, vitB, W2, nullptr, X2, BB * NVV, DD, DD, DD, DD, DD,
             1.f, nullptr, nullptr, nullptr, 0, 0);
    // ctxB = P @ vB (batched, non-trans B)
    gemm(stream, false, PB, X2, nullptr, X1, LL, DD, NVV, 200, DD, DD,
         BB, (long long)LL * 200, sB_NV, sA_L, 1.f, nullptr, nullptr, nullptr, 0, 0);
    // tii_pre += ctxB @ W3^T (+ TFB residual at h==0)
    gemm128h(stream, X1, W3, R_ACC, nullptr, BB * LL, DD, DD, DD, DD, DD,
             1.f, nullptr, (h == 0 ? TFB : nullptr), nullptr, 0, (h > 0 ? 1 : 0));
  }

  // 3. tii = LN(tii_pre) in-place f32 + fused row norms
  ln_kernel<<<BB * LL, 256, 0, stream>>>(R_ACC, R_ACC, nullptr, mha_ln_g, mha_ln_b, nrm);
  // 4. adj_ti = adj * cos-sim (fused GEMM epilogue), bf16
  sim_kernel<<<dim3(3, 3, BB), 256, 0, stream>>>(R_ACC, nrm, adj, adjtiB);
  // 5. den, den_ti
  den_kernel<<<BB * LL, 256, 0, stream>>>(adj, adjtiB, den, den_ti);
  // 6. span pools (direct span sums)
  pool_kernel<u16><<<dim3(BB, LL), 256, 0, stream>>>(TFB, tmpsB, word_length, tran);
  pool_kernel<float><<<dim3(BB, LL), 256, 0, stream>>>(R_ACC, tmpsTiB, word_length, tran);
  // 7. h1 = adj @ tmps (batched), h2 = adj_ti @ tmps_ti
  gemm(stream, false, adjB, tmpsB, nullptr, h1B, LL, DD, LL, LL, DD, DD,
       BB, (long long)LL * LL, sA_L, sA_L, 1.f, nullptr, nullptr, nullptr, 0, 0);
  gemm(stream, false, adjtiB, tmpsTiB, nullptr, h2B, LL, DD, LL, LL, DD, DD,
       BB, (long long)LL * LL, sA_L, sA_L, 1.f, nullptr, nullptr, nullptr, 0, 0);
  // 8. g1 = relu((h1 @ w1b + b1b) / den); g2 likewise (flat 128x128 path)
  gemm128h(stream, h1B, w1bT, nullptr, g1B, BB * LL, DD, DD, DD, DD, DD,
           1.f, b1b, nullptr, den, 1, 0);
  gemm128h(stream, h2B, w2bT, nullptr, g2B, BB * LL, DD, DD, DD, DD, DD,
           1.f, b2b, nullptr, den_ti, 1, 0);
  // 9. masked means -> local_in bf16 (B,1536)
  gcn_kernel<<<dim3(BB, 3), 256, 0, stream>>>(g1B, target_mask, linB, 0);
  gcn_kernel<<<dim3(BB, 3), 256, 0, stream>>>(g2B, target_mask, linB, DD);
  // 10. global_bert = LN(pooler_out) f32
  ln_kernel<<<BB, 256, 0, stream>>>(pooler_out, global_bert, nullptr, ln_g, ln_b, nullptr);
  // 11. local_feat = local_in @ loc_w + loc_b (f32 out)
  gemm(stream, true, linB, locT, local_feat, nullptr, BB, DD, 2 * DD, 2 * DD, 2 * DD, DD,
       1, 0, 0, 0, 1.f, loc_b, nullptr, nullptr, 0, 0);
  // 12. out
  final_kernel<<<BB * 3, 256, 0, stream>>>(global_bert, local_feat, out_w, out_b, out);
}

// Round 6
// 1348.579 us; speedup vs baseline: 1.0962x; 1.0962x over previous
//
#include <hip/hip_runtime.h>
#include <math.h>

#define BB 64
#define LL 160
#define DD 768
#define HH 4
#define NVV 197
#define SS 159

typedef unsigned short u16;
typedef __attribute__((ext_vector_type(8))) short bf16x8;
typedef __attribute__((ext_vector_type(4))) float f32x4;

union QU { uint4 u; bf16x8 v; };

__device__ __forceinline__ u16 f2bf(float a) {
  unsigned u = __builtin_bit_cast(unsigned, a);
  u = (u + 0x7FFFu + ((u >> 16) & 1u)) >> 16;
  return (u16)u;
}
__device__ __forceinline__ unsigned f2bf2(float a, float b) {
  return (unsigned)f2bf(a) | ((unsigned)f2bf(b) << 16);
}
__device__ __forceinline__ float bf2f(u16 h) {
  unsigned u = ((unsigned)h) << 16;
  return __builtin_bit_cast(float, u);
}
__device__ __forceinline__ float to_f(float x) { return x; }
__device__ __forceinline__ float to_f(u16 x) { return bf2f(x); }

__device__ __forceinline__ void async16(const u16* g, void* l) {
  __builtin_amdgcn_global_load_lds(
      (const __attribute__((address_space(1))) void*)g,
      (__attribute__((address_space(3))) void*)l, 16, 0, 0);
}

__device__ __forceinline__ uint4 load_bf8(const u16* __restrict__ P, long long rowbase,
                                          int valid, int kb, int K) {
  uint4 r;
  if (valid && (kb + 8 <= K) && (((rowbase + kb) & 7) == 0)) {
    r = *(const uint4*)(P + rowbase + kb);
  } else {
    u16 e[8];
    #pragma unroll
    for (int i = 0; i < 8; ++i) { int k = kb + i; e[i] = (valid && k < K) ? P[rowbase + k] : (u16)0; }
    r.x = e[0] | ((unsigned)e[1] << 16); r.y = e[2] | ((unsigned)e[3] << 16);
    r.z = e[4] | ((unsigned)e[5] << 16); r.w = e[6] | ((unsigned)e[7] << 16);
  }
  return r;
}

__device__ __forceinline__ uint4 load_row8(const float* __restrict__ P, long long rowbase,
                                           int valid_row, int kb, int K) {
  float f[8];
  if (valid_row && (kb + 8 <= K)) {
    const float4* p0 = (const float4*)(P + rowbase + kb);
    float4 x = p0[0], y = p0[1];
    f[0] = x.x; f[1] = x.y; f[2] = x.z; f[3] = x.w;
    f[4] = y.x; f[5] = y.y; f[6] = y.z; f[7] = y.w;
  } else {
    #pragma unroll
    for (int e = 0; e < 8; ++e) { int k = kb + e; f[e] = (valid_row && k < K) ? P[rowbase + k] : 0.f; }
  }
  uint4 r;
  r.x = f2bf2(f[0], f[1]); r.y = f2bf2(f[2], f[3]);
  r.z = f2bf2(f[4], f[5]); r.w = f2bf2(f[6], f[7]);
  return r;
}

// ---------------- 128x128 MFMA GEMM, 3-deep pipelined global_load_lds, TRANSB ----------------
// C = alpha * A @ B^T (+bias) (+residB) (+=Cf if accum) (/rowdiv) (relu)
__global__ __launch_bounds__(256) void gemm128p(
    const u16* __restrict__ A, const u16* __restrict__ Bm,
    float* __restrict__ Cf, u16* __restrict__ Cb,
    int M, int N, int K, int lda, int ldb, int ldc, int nbx,
    float alpha, const float* __restrict__ bias, const u16* __restrict__ residB,
    const float* __restrict__ rowdiv, int relu, int accum) {
  __shared__ uint4 As[3][4][128];  // [buf][kg][row] : 8 bf16 at k = k0+kg*8
  __shared__ uint4 Bs[3][4][128];

  // flatten + bijective XCD swizzle
  int nwg = gridDim.x;
  int id = blockIdx.x;
  int qq = nwg >> 3, rr = nwg & 7;
  int xcd = id & 7, idx = id >> 3;
  int swz = (xcd < rr ? xcd * (qq + 1) : rr * (qq + 1) + (xcd - rr) * qq) + idx;
  int bx = swz % nbx, by = swz / nbx;
  int row0 = by * 128, col0 = bx * 128;

  int t = threadIdx.x, l = t & 63, w = t >> 6;
  int wr = (w >> 1) * 64, wc = (w & 1) * 64;
  int nt = K >> 5;  // K multiple of 32

  // clamped per-lane source rows so every stage issues exactly 4 loads/wave
  int ra0 = row0 + l;       if (ra0 > M - 1) ra0 = M - 1;
  int ra1 = row0 + 64 + l;  if (ra1 > M - 1) ra1 = M - 1;
  int rb0 = col0 + l;       if (rb0 > N - 1) rb0 = N - 1;
  int rb1 = col0 + 64 + l;  if (rb1 > N - 1) rb1 = N - 1;
  const u16* Ab0 = A + (long long)ra0 * lda + w * 8;
  const u16* Ab1 = A + (long long)ra1 * lda + w * 8;
  const u16* Bb0 = Bm + (long long)rb0 * ldb + w * 8;
  const u16* Bb1 = Bm + (long long)rb1 * ldb + w * 8;

  f32x4 acc[4][4] = {};

  // prologue: stage 0 and 1
  async16(Ab0, &As[0][w][0]);  async16(Ab1, &As[0][w][64]);
  async16(Bb0, &Bs[0][w][0]);  async16(Bb1, &Bs[0][w][64]);
  if (nt > 1) {
    async16(Ab0 + 32, &As[1][w][0]);  async16(Ab1 + 32, &As[1][w][64]);
    async16(Bb0 + 32, &Bs[1][w][0]);  async16(Bb1 + 32, &Bs[1][w][64]);
  }

  for (int tt = 0; tt < nt; ++tt) {
    int rem = nt - 1 - tt;
    if (rem >= 1) asm volatile("s_waitcnt vmcnt(4)" ::: "memory");
    else          asm volatile("s_waitcnt vmcnt(0)" ::: "memory");
    __builtin_amdgcn_s_barrier();
    if (rem >= 2) {
      int kk = (tt + 2) << 5;
      int buf = (tt + 2) % 3;
      async16(Ab0 + kk, &As[buf][w][0]);  async16(Ab1 + kk, &As[buf][w][64]);
      async16(Bb0 + kk, &Bs[buf][w][0]);  async16(Bb1 + kk, &Bs[buf][w][64]);
    }
    int buf = tt % 3;
    int kg = l >> 4, li = l & 15;
    QU a[4], b[4];
    #pragma unroll
    for (int i = 0; i < 4; ++i) a[i].u = As[buf][kg][wr + i * 16 + li];
    #pragma unroll
    for (int j = 0; j < 4; ++j) b[j].u = Bs[buf][kg][wc + j * 16 + li];
    #pragma unroll
    for (int i = 0; i < 4; ++i)
      #pragma unroll
      for (int j = 0; j < 4; ++j)
        acc[i][j] = __builtin_amdgcn_mfma_f32_16x16x32_bf16(a[i].v, b[j].v, acc[i][j], 0, 0, 0);
  }

  #pragma unroll
  for (int i = 0; i < 4; ++i) {
    #pragma unroll
    for (int j = 0; j < 4; ++j) {
      int colj = col0 + wc + j * 16 + (l & 15);
      float bv = (bias && colj < N) ? bias[colj] : 0.f;
      #pragma unroll
      for (int r = 0; r < 4; ++r) {
        int gr = row0 + wr + i * 16 + (l >> 4) * 4 + r;
        if (gr < M && colj < N) {
          long long ci = (long long)gr * ldc + colj;
          float v = acc[i][j][r] * alpha + bv;
          if (residB) v += bf2f(residB[ci]);
          if (accum) v += Cf[ci];
          if (rowdiv) v /= rowdiv[gr];
          if (relu) v = fmaxf(v, 0.f);
          if (Cf) Cf[ci] = v;
          if (Cb) Cb[ci] = f2bf(v);
        }
      }
    }
  }
}

// ---------------- bf16 MFMA GEMM, 64x64 tile, batched ----------------
template<bool TRANSB>
__global__ __launch_bounds__(256) void gemm_bf16(
    const u16* __restrict__ A, const u16* __restrict__ Bm,
    float* __restrict__ Cf, u16* __restrict__ Cb,
    int M, int N, int K, int lda, int ldb, int ldc,
    long long sAb, long long sBb, long long sCb,
    float alpha, const float* __restrict__ bias, const u16* __restrict__ residB,
    const float* __restrict__ rowdiv, int relu, int accum) {
  int bb = blockIdx.z;
  A += bb * sAb;
  Bm += bb * sBb;
  long long coff = bb * sCb;

  __shared__ uint4 As4[4][64];
  __shared__ uint4 Bs4[4][64];

  int row0 = blockIdx.y * 64, col0 = blockIdx.x * 64;
  int t = threadIdx.x;
  int l = t & 63, w = t >> 6;
  int mq = (w >> 1) * 32, nq = (w & 1) * 32;

  int am = t >> 2, akq = t & 3;
  int bn = t & 63, bkq = t >> 6;

  f32x4 acc[2][2] = {};

  for (int k0 = 0; k0 < K; k0 += 32) {
    As4[akq][am] = load_bf8(A, (long long)(row0 + am) * lda, (row0 + am) < M, k0 + akq * 8, K);
    if (TRANSB) {
      Bs4[akq][am] = load_bf8(Bm, (long long)(col0 + am) * ldb, (col0 + am) < N, k0 + akq * 8, K);
    } else {
      int gn = col0 + bn;
      u16 e[8];
      #pragma unroll
      for (int i = 0; i < 8; ++i) {
        int k = k0 + bkq * 8 + i;
        e[i] = (gn < N && k < K) ? Bm[(long long)k * ldb + gn] : (u16)0;
      }
      uint4 r;
      r.x = e[0] | ((unsigned)e[1] << 16); r.y = e[2] | ((unsigned)e[3] << 16);
      r.z = e[4] | ((unsigned)e[5] << 16); r.w = e[6] | ((unsigned)e[7] << 16);
      Bs4[bkq][bn] = r;
    }
    __syncthreads();
    int kg = l >> 4, li = l & 15;
    QU a0, a1, b0, b1;
    a0.u = As4[kg][mq + li];
    a1.u = As4[kg][mq + 16 + li];
    b0.u = Bs4[kg][nq + li];
    b1.u = Bs4[kg][nq + 16 + li];
    acc[0][0] = __builtin_amdgcn_mfma_f32_16x16x32_bf16(a0.v, b0.v, acc[0][0], 0, 0, 0);
    acc[0][1] = __builtin_amdgcn_mfma_f32_16x16x32_bf16(a0.v, b1.v, acc[0][1], 0, 0, 0);
    acc[1][0] = __builtin_amdgcn_mfma_f32_16x16x32_bf16(a1.v, b0.v, acc[1][0], 0, 0, 0);
    acc[1][1] = __builtin_amdgcn_mfma_f32_16x16x32_bf16(a1.v, b1.v, acc[1][1], 0, 0, 0);
    __syncthreads();
  }

  #pragma unroll
  for (int i = 0; i < 2; ++i) {
    #pragma unroll
    for (int j = 0; j < 2; ++j) {
      int colj = col0 + nq + j * 16 + (l & 15);
      float bv = (bias && colj < N) ? bias[colj] : 0.f;
      #pragma unroll
      for (int r = 0; r < 4; ++r) {
        int gr = row0 + mq + i * 16 + (l >> 4) * 4 + r;
        if (gr < M && colj < N) {
          long long ci = coff + (long long)gr * ldc + colj;
          float v = acc[i][j][r] * alpha + bv;
          if (residB) v += bf2f(residB[ci]);
          if (accum) v += Cf[ci];
          if (rowdiv) v /= rowdiv[gr];
          if (relu) v = fmaxf(v, 0.f);
          if (Cf) Cf[ci] = v;
          if (Cb) Cb[ci] = f2bf(v);
        }
      }
    }
  }
}

// ---------------- sim GEMM (f32 in) fused with cosine*adj epilogue -> adj_ti bf16 ----------------
__global__ __launch_bounds__(256) void sim_kernel(
    const float* __restrict__ TII, const float* __restrict__ nrm,
    const float* __restrict__ adjf, u16* __restrict__ adjtiB) {
  int bb = blockIdx.z;
  const float* T = TII + (long long)bb * LL * DD;

  __shared__ uint4 As4[4][64];
  __shared__ uint4 Bs4[4][64];

  int row0 = blockIdx.y * 64, col0 = blockIdx.x * 64;
  int t = threadIdx.x;
  int l = t & 63, w = t >> 6;
  int mq = (w >> 1) * 32, nq = (w & 1) * 32;
  int am = t >> 2, akq = t & 3;

  f32x4 acc[2][2] = {};

  for (int k0 = 0; k0 < DD; k0 += 32) {
    As4[akq][am] = load_row8(T, (long long)(row0 + am) * DD, (row0 + am) < LL, k0 + akq * 8, DD);
    Bs4[akq][am] = load_row8(T, (long long)(col0 + am) * DD, (col0 + am) < LL, k0 + akq * 8, DD);
    __syncthreads();
    int kg = l >> 4, li = l & 15;
    QU a0, a1, b0, b1;
    a0.u = As4[kg][mq + li];
    a1.u = As4[kg][mq + 16 + li];
    b0.u = Bs4[kg][nq + li];
    b1.u = Bs4[kg][nq + 16 + li];
    acc[0][0] = __builtin_amdgcn_mfma_f32_16x16x32_bf16(a0.v, b0.v, acc[0][0], 0, 0, 0);
    acc[0][1] = __builtin_amdgcn_mfma_f32_16x16x32_bf16(a0.v, b1.v, acc[0][1], 0, 0, 0);
    acc[1][0] = __builtin_amdgcn_mfma_f32_16x16x32_bf16(a1.v, b0.v, acc[1][0], 0, 0, 0);
    acc[1][1] = __builtin_amdgcn_mfma_f32_16x16x32_bf16(a1.v, b1.v, acc[1][1], 0, 0, 0);
    __syncthreads();
  }

  #pragma unroll
  for (int i = 0; i < 2; ++i) {
    #pragma unroll
    for (int j = 0; j < 2; ++j) {
      int colj = col0 + nq + j * 16 + (l & 15);
      #pragma unroll
      for (int r = 0; r < 4; ++r) {
        int gr = row0 + mq + i * 16 + (l >> 4) * 4 + r;
        if (gr < LL && colj < LL) {
          float nl = nrm[bb * LL + gr], nm = nrm[bb * LL + colj];
          long long ai = ((long long)bb * LL + gr) * LL + colj;
          float s = acc[i][j][r] / fmaxf(nl * nm, 1e-16f);
          adjtiB[ai] = f2bf(adjf[ai] * s);
        }
      }
    }
  }
}

// ---------------- block reduce ----------------
__device__ __forceinline__ float block_sum(float v, float* sm) {
  #pragma unroll
  for (int o = 32; o > 0; o >>= 1) v += __shfl_down(v, o);
  int lane = threadIdx.x & 63, w = threadIdx.x >> 6;
  if (lane == 0) sm[w] = v;
  __syncthreads();
  if (threadIdx.x == 0) sm[0] = sm[0] + sm[1] + sm[2] + sm[3];
  __syncthreads();
  float r = sm[0];
  __syncthreads();
  return r;
}

// ---------------- LayerNorm ----------------
__global__ __launch_bounds__(256) void ln_kernel(const float* __restrict__ x, float* __restrict__ yf,
                                                 u16* __restrict__ yb,
                                                 const float* __restrict__ g, const float* __restrict__ b,
                                                 float* __restrict__ nrmout) {
  __shared__ float sm[4];
  long long row = blockIdx.x;
  const float* xr = x + row * DD;
  int t = threadIdx.x;
  float v0 = xr[t], v1 = xr[t + 256], v2 = xr[t + 512];
  float s = block_sum(v0 + v1 + v2, sm);
  float m = s * (1.f / 768.f);
  float d0 = v0 - m, d1 = v1 - m, d2 = v2 - m;
  float vv = block_sum(d0 * d0 + d1 * d1 + d2 * d2, sm);
  float rstd = rsqrtf(vv * (1.f / 768.f) + 1e-5f);
  float y0 = d0 * rstd * g[t] + b[t];
  float y1 = d1 * rstd * g[t + 256] + b[t + 256];
  float y2 = d2 * rstd * g[t + 512] + b[t + 512];
  if (yf) { float* yr = yf + row * DD; yr[t] = y0; yr[t + 256] = y1; yr[t + 512] = y2; }
  if (yb) { u16* yr = yb + row * DD; yr[t] = f2bf(y0); yr[t + 256] = f2bf(y1); yr[t + 512] = f2bf(y2); }
  if (nrmout) {
    float s2 = block_sum(y0 * y0 + y1 * y1 + y2 * y2, sm);
    if (t == 0) nrmout[row] = sqrtf(s2);
  }
}

// ---------------- softmax f32 in -> bf16 out (ld 200) ----------------
__global__ __launch_bounds__(256) void softmax_kernel(const float* __restrict__ S, u16* __restrict__ PB,
                                                      int nrows) {
  int row = blockIdx.x * 4 + (threadIdx.x >> 6);
  int lane = threadIdx.x & 63;
  if (row >= nrows) return;
  const float* ar = S + (long long)row * NVV;
  u16* pr = PB + (long long)row * 200;
  float vals[4];
  float mx = -1e30f;
  int cnt = 0;
  for (int i = lane; i < NVV; i += 64) { float v = ar[i]; vals[cnt++] = v; mx = fmaxf(mx, v); }
  #pragma unroll
  for (int o = 32; o > 0; o >>= 1) mx = fmaxf(mx, __shfl_xor(mx, o));
  float sum = 0.f;
  for (int j = 0; j < cnt; ++j) { vals[j] = __expf(vals[j] - mx); sum += vals[j]; }
  #pragma unroll
  for (int o = 32; o > 0; o >>= 1) sum += __shfl_xor(sum, o);
  float inv = 1.f / sum;
  cnt = 0;
  for (int i = lane; i < NVV; i += 64) pr[i] = f2bf(vals[cnt++] * inv);
  for (int i = NVV + lane; i < 200; i += 64) pr[i] = 0;
}

// ---------------- direct span-sum pool ----------------
template<typename T>
__global__ __launch_bounds__(256) void pool_kernel(const T* __restrict__ src, u16* __restrict__ dst,
                                                   const int* __restrict__ wl, const int* __restrict__ tran) {
  int b = blockIdx.x, i = blockIdx.y, d = threadIdx.x;
  long long ob = ((long long)b * LL + i) * DD;
  float r0 = 0.f, r1 = 0.f, r2 = 0.f;
  if (i > 0 && (i - 1) < wl[b]) {
    int w = i - 1;
    int st = tran[(b * SS + w) * 2];
    int en = tran[(b * SS + w) * 2 + 1];
    const T* sb = src + (long long)b * LL * DD;
    for (int s = st; s < en; ++s) {
      const T* rp = sb + (long long)(1 + s) * DD;
      r0 += to_f(rp[d]); r1 += to_f(rp[d + 256]); r2 += to_f(rp[d + 512]);
    }
  }
  dst[ob + d] = f2bf(r0);
  dst[ob + d + 256] = f2bf(r1);
  dst[ob + d + 512] = f2bf(r2);
}

// ---------------- den / den_ti ----------------
__global__ __launch_bounds__(256) void den_kernel(const float* __restrict__ adjf, const u16* __restrict__ atB,
                                                  float* __restrict__ den, float* __restrict__ den_ti) {
  __shared__ float sm[4];
  int bl = blockIdx.x, m = threadIdx.x;
  float a = 0.f, at = 0.f;
  if (m < LL) {
    long long idx = (long long)bl * LL + m;
    a = adjf[idx];
    at = bf2f(atB[idx]);
  }
  float sa = block_sum(a, sm);
  float sat = block_sum(at, sm);
  if (m == 0) { den[bl] = sa + 1.f; den_ti[bl] = sat + 1.f; }
}

// ---------------- masked mean ----------------
__global__ __launch_bounds__(256) void gcn_kernel(const u16* __restrict__ g, const float* __restrict__ mask,
                                                  u16* __restrict__ outB, int coloff) {
  int b = blockIdx.x;
  int d = blockIdx.y * 256 + threadIdx.x;
  float s = 0.f, wn = 0.f;
  for (int l = 0; l < LL; ++l) {
    float mk = mask[b * LL + l];
    wn += mk;
    s += mk * bf2f(g[((long long)b * LL + l) * DD + d]);
  }
  outB[(long long)b * (2 * DD) + coloff + d] = f2bf(s / wn);
}

// ---------------- final ----------------
__global__ __launch_bounds__(256) void final_kernel(const float* __restrict__ gb, const float* __restrict__ lf,
                                                    const float* __restrict__ ow, const float* __restrict__ ob,
                                                    float* __restrict__ out) {
  __shared__ float sm[4];
  int b = blockIdx.x / 3, c = blockIdx.x % 3;
  int t = threadIdx.x;
  float s = 0.f;
  for (int k = t; k < DD; k += 256) {
    s += gb[b * DD + k] * ow[k * 3 + c];
    s += lf[b * DD + k] * ow[(DD + k) * 3 + c];
  }
  float tot = block_sum(s, sm);
  if (t == 0) out[b * 3 + c] = tot + ob[c];
}

// ---------------- f32 -> bf16 elementwise ----------------
__global__ __launch_bounds__(256) void conv_kernel(const float4* __restrict__ x, uint2* __restrict__ y, int n4) {
  int i = blockIdx.x * 256 + threadIdx.x;
  if (i < n4) {
    float4 v = x[i];
    uint2 o;
    o.x = f2bf2(v.x, v.y);
    o.y = f2bf2(v.z, v.w);
    y[i] = o;
  }
}

// ---------------- transpose-convert ----------------
__global__ __launch_bounds__(256) void tconv_kernel(const float* __restrict__ src, u16* __restrict__ dst,
                                                    int R, int C, int lds, int ldd) {
  __shared__ float sm[32][33];
  int t = threadIdx.x;
  int tx = t & 31, ty8 = t >> 5;
  int r0 = blockIdx.y * 32, c0 = blockIdx.x * 32;
  for (int i = ty8; i < 32; i += 8) {
    int r = r0 + i, c = c0 + tx;
    sm[i][tx] = (r < R && c < C) ? src[(long long)r * lds + c] : 0.f;
  }
  __syncthreads();
  for (int i = ty8; i < 32; i += 8) {
    int c = c0 + i, r = r0 + tx;
    if (c < C && r < R) dst[(long long)c * ldd + r] = f2bf(sm[tx][i]);
  }
}

// ---------------- host wrappers ----------------
static void gemm(hipStream_t s, bool transb, const u16* A, const u16* B, float* Cf, u16* Cb,
                 int M, int N, int K, int lda, int ldb, int ldc, int batches,
                 long long sAb, long long sBb, long long sCb, float alpha,
                 const float* bias, const u16* residB, const float* rowdiv, int relu, int accum) {
  dim3 g((N + 63) / 64, (M + 63) / 64, batches);
  if (transb)
    gemm_bf16<true><<<g, 256, 0, s>>>(A, B, Cf, Cb, M, N, K, lda, ldb, ldc, sAb, sBb, sCb,
                                      alpha, bias, residB, rowdiv, relu, accum);
  else
    gemm_bf16<false><<<g, 256, 0, s>>>(A, B, Cf, Cb, M, N, K, lda, ldb, ldc, sAb, sBb, sCb,
                                       alpha, bias, residB, rowdiv, relu, accum);
}

static void gemm128ph(hipStream_t s, const u16* A, const u16* B, float* Cf, u16* Cb,
                      int M, int N, int K, int lda, int ldb, int ldc, float alpha,
                      const float* bias, const u16* residB, const float* rowdiv,
                      int relu, int accum) {
  int nbx = (N + 127) / 128, nby = (M + 127) / 128;
  gemm128p<<<nbx * nby, 256, 0, s>>>(A, B, Cf, Cb, M, N, K, lda, ldb, ldc, nbx,
                                     alpha, bias, residB, rowdiv, relu, accum);
}

extern "C" void kernel_launch(void* const* d_in, const int* in_sizes, int n_in,
                              void* d_out, int out_size, void* d_ws, size_t ws_size,
                              hipStream_t stream) {
  const float* text_hidden = (const float*)d_in[0];
  const float* vit_feature = (const float*)d_in[1];
  const float* pooler_out = (const float*)d_in[2];
  const float* target_mask = (const float*)d_in[3];
  const float* adj = (const float*)d_in[4];
  const float* ln_g = (const float*)d_in[5];
  const float* ln_b = (const float*)d_in[6];
  const float* wq = (const float*)d_in[7];
  const float* wk = (const float*)d_in[8];
  const float* wv = (const float*)d_in[9];
  const float* fc_w = (const float*)d_in[10];
  const float* mha_ln_g = (const float*)d_in[11];
  const float* mha_ln_b = (const float*)d_in[12];
  const float* w1b = (const float*)d_in[15];
  const float* b1b = (const float*)d_in[16];
  const float* w2b = (const float*)d_in[19];
  const float* b2b = (const float*)d_in[20];
  const float* loc_w = (const float*)d_in[21];
  const float* loc_b = (const float*)d_in[22];
  const float* out_w = (const float*)d_in[23];
  const float* out_b = (const float*)d_in[24];
  const int* word_length = (const int*)d_in[25];
  const int* tran = (const int*)d_in[26];
  float* out = (float*)d_out;

  const long long BLD = (long long)BB * LL * DD;
  const long long BND = (long long)BB * NVV * DD;

  const size_t NEED_BIG = 165000000;  // exact big layout = 164.04 MB
  bool big = (ws_size >= NEED_BIG);

  char* base = (char*)d_ws;
  auto alloc = [&](size_t bytes) { char* p = base; base += (bytes + 255) & ~(size_t)255; return p; };

  float* R_ACC = (float*)alloc(BLD * 4);
  float* R_S = (float*)alloc((size_t)BB * LL * NVV * 4);
  u16* TFB = (u16*)alloc(BLD * 2);
  u16* vitB = (u16*)alloc(BND * 2);
  u16* X1 = (u16*)alloc(BLD * 2);
  u16* kvB = (u16*)alloc(big ? (size_t)BB * NVV * 1536 * 2 : (size_t)BND * 2);
  u16* PB = (u16*)alloc((size_t)BB * LL * 200 * 2);
  u16* adjB = (u16*)alloc((size_t)BB * LL * LL * 2);
  u16* adjtiB = (u16*)alloc((size_t)BB * LL * LL * 2);
  u16 *wqT = nullptr, *wkvT = nullptr, *fcT = nullptr;
  u16 *W0 = nullptr, *W1 = nullptr, *W2 = nullptr, *W3 = nullptr;
  if (big) {
    wqT = (u16*)alloc((size_t)3072 * 768 * 2);
    wkvT = (u16*)alloc((size_t)4 * 1536 * 768 * 2);
    fcT = (u16*)alloc((size_t)4 * 768 * 768 * 2);
  } else {
    W0 = (u16*)alloc((size_t)768 * 768 * 2);
    W1 = (u16*)alloc((size_t)768 * 768 * 2);
    W2 = (u16*)alloc((size_t)768 * 768 * 2);
    W3 = (u16*)alloc((size_t)768 * 768 * 2);
  }
  u16* w1bT = (u16*)alloc((size_t)768 * 768 * 2);
  u16* w2bT = (u16*)alloc((size_t)768 * 768 * 2);
  u16* locT = (u16*)alloc((size_t)768 * 1536 * 2);
  u16* linB = (u16*)alloc((size_t)BB * 1536 * 2);
  float* nrm = (float*)alloc((size_t)BB * LL * 4);
  float* den = (float*)alloc((size_t)BB * LL * 4);
  float* den_ti = (float*)alloc((size_t)BB * LL * 4);
  float* global_bert = (float*)alloc((size_t)BB * DD * 4);
  float* local_feat = (float*)alloc((size_t)BB * DD * 4);
  u16* tmpsB = vitB;
  u16* tmpsTiB = X1;
  u16* h1B = kvB;
  u16* h2B = TFB;
  u16* g1B = vitB;
  u16* g2B = X1;

  const float inv_sqrt_d = 1.0f / sqrtf((float)DD);
  const long long sA_L = (long long)LL * DD;

  // one-time conversions
  {
    int n4 = (int)(BND / 4);
    conv_kernel<<<(n4 + 255) / 256, 256, 0, stream>>>((const float4*)vit_feature, (uint2*)vitB, n4);
    int n4a = (int)((long long)BB * LL * LL / 4);
    conv_kernel<<<(n4a + 255) / 256, 256, 0, stream>>>((const float4*)adj, (uint2*)adjB, n4a);
    tconv_kernel<<<dim3(24, 24), 256, 0, stream>>>(w1b, w1bT, 768, 768, 768, 768);
    tconv_kernel<<<dim3(24, 24), 256, 0, stream>>>(w2b, w2bT, 768, 768, 768, 768);
    tconv_kernel<<<dim3(24, 48), 256, 0, stream>>>(loc_w, locT, 1536, 768, 768, 1536);
    if (big) {
      tconv_kernel<<<dim3(96, 24), 256, 0, stream>>>(wq, wqT, 768, 3072, 3072, 768);
      for (int h = 0; h < HH; ++h) {
        tconv_kernel<<<dim3(24, 24), 256, 0, stream>>>(wk + h * 768, wkvT + (size_t)h * 1536 * 768,
                                                       768, 768, 3072, 768);
        tconv_kernel<<<dim3(24, 24), 256, 0, stream>>>(wv + h * 768, wkvT + (size_t)h * 1536 * 768 + 768 * 768,
                                                       768, 768, 3072, 768);
        tconv_kernel<<<dim3(24, 24), 256, 0, stream>>>(fc_w + (size_t)h * 768 * 768, fcT + (size_t)h * 768 * 768,
                                                       768, 768, 768, 768);
      }
    }
  }

  // 1. text_feat = LN(text_hidden) -> bf16
  ln_kernel<<<BB * LL, 256, 0, stream>>>(text_hidden, nullptr, TFB, ln_g, ln_b, nullptr);

  // 2. per-head attention, accumulating pre-LN tii (f32)
  for (int h = 0; h < HH; ++h) {
    const u16 *qW, *kW, *vW, *fW;
    if (big) {
      qW = wqT + (size_t)h * 768 * 768;
      kW = wkvT + (size_t)h * 1536 * 768;
      vW = kW + 768 * 768;
      fW = fcT + (size_t)h * 768 * 768;
    } else {
      tconv_kernel<<<dim3(24, 24), 256, 0, stream>>>(wq + h * 768, W0, 768, 768, 3072, 768);
      tconv_kernel<<<dim3(24, 24), 256, 0, stream>>>(wk + h * 768, W1, 768, 768, 3072, 768);
      tconv_kernel<<<dim3(24, 24), 256, 0, stream>>>(wv + h * 768, W2, 768, 768, 3072, 768);
      tconv_kernel<<<dim3(24, 24), 256, 0, stream>>>(fc_w + (size_t)h * 768 * 768, W3, 768, 768, 768, 768);
      qW = W0; kW = W1; vW = W2; fW = W3;
    }
    // qB = TFB @ qW^T
    gemm128ph(stream, TFB, qW, nullptr, X1, BB * LL, DD, DD, DD, DD, DD,
              1.f, nullptr, nullptr, nullptr, 0, 0);
    int kvld = big ? 1536 : 768;
    if (big) {
      // kv merged: one N=1536 GEMM
      gemm128ph(stream, vitB, kW, nullptr, kvB, BB * NVV, 1536, DD, DD, DD, 1536,
                1.f, nullptr, nullptr, nullptr, 0, 0);
    } else {
      gemm128ph(stream, vitB, kW, nullptr, kvB, BB * NVV, DD, DD, DD, DD, DD,
                1.f, nullptr, nullptr, nullptr, 0, 0);
    }
    // S = qB @ k^T / sqrt(D)
    gemm(stream, true, X1, kvB, R_S, nullptr, LL, NVV, DD, DD, kvld, NVV,
         BB, sA_L, (long long)NVV * kvld, (long long)LL * NVV,
         inv_sqrt_d, nullptr, nullptr, nullptr, 0, 0);
    softmax_kernel<<<(BB * LL + 3) / 4, 256, 0, stream>>>(R_S, PB, BB * LL);
    if (!big) {
      // v overwrites k
      gemm128ph(stream, vitB, vW, nullptr, kvB, BB * NVV, DD, DD, DD, DD, DD,
                1.f, nullptr, nullptr, nullptr, 0, 0);
    }
    const u16* vptr = big ? kvB + 768 : kvB;
    // ctxB = P @ v
    gemm(stream, false, PB, vptr, nullptr, X1, LL, DD, NVV, 200, kvld, DD,
         BB, (long long)LL * 200, (long long)NVV * kvld, sA_L,
         1.f, nullptr, nullptr, nullptr, 0, 0);
    // tii_pre += ctxB @ fW^T (+ TFB residual at h==0)
    gemm128ph(stream, X1, fW, R_ACC, nullptr, BB * LL, DD, DD, DD, DD, DD,
              1.f, nullptr, (h == 0 ? TFB : nullptr), nullptr, 0, (h > 0 ? 1 : 0));
  }

  // 3. tii = LN(tii_pre) + fused row norms
  ln_kernel<<<BB * LL, 256, 0, stream>>>(R_ACC, R_ACC, nullptr, mha_ln_g, mha_ln_b, nrm);
  // 4. adj_ti = adj * cos-sim
  sim_kernel<<<dim3(3, 3, BB), 256, 0, stream>>>(R_ACC, nrm, adj, adjtiB);
  // 5. den, den_ti
  den_kernel<<<BB * LL, 256, 0, stream>>>(adj, adjtiB, den, den_ti);
  // 6. span pools
  pool_kernel<u16><<<dim3(BB, LL), 256, 0, stream>>>(TFB, tmpsB, word_length, tran);
  pool_kernel<float><<<dim3(BB, LL), 256, 0, stream>>>(R_ACC, tmpsTiB, word_length, tran);
  // 7. h1 = adj @ tmps (batched), h2 = adj_ti @ tmps_ti
  gemm(stream, false, adjB, tmpsB, nullptr, h1B, LL, DD, LL, LL, DD, DD,
       BB, (long long)LL * LL, sA_L, sA_L, 1.f, nullptr, nullptr, nullptr, 0, 0);
  gemm(stream, false, adjtiB, tmpsTiB, nullptr, h2B, LL, DD, LL, LL, DD, DD,
       BB, (long long)LL * LL, sA_L, sA_L, 1.f, nullptr, nullptr, nullptr, 0, 0);
  // 8. g1 = relu((h1 @ w1b + b1b) / den); g2 likewise
  gemm128ph(stream, h1B, w1bT, nullptr, g1B, BB * LL, DD, DD, DD, DD, DD,
            1.f, b1b, nullptr, den, 1, 0);
  gemm128ph(stream, h2B, w2bT, nullptr, g2B, BB * LL, DD, DD, DD, DD, DD,
            1.f, b2b, nullptr, den_ti, 1, 0);
  // 9. masked means -> local_in bf16
  gcn_kernel<<<dim3(BB, 3), 256, 0, stream>>>(g1B, target_mask, linB, 0);
  gcn_kernel<<<dim3(BB, 3), 256, 0, stream>>>(g2B, target_mask, linB, DD);
  // 10. global_bert = LN(pooler_out)
  ln_kernel<<<BB, 256, 0, stream>>>(pooler_out, global_bert, nullptr, ln_g, ln_b, nullptr);
  // 11. local_feat = local_in @ loc_w + loc_b
  gemm(stream, true, linB, locT, local_feat, nullptr, BB, DD, 2 * DD, 2 * DD, 2 * DD, DD,
       1, 0, 0, 0, 1.f, loc_b, nullptr, nullptr, 0, 0);
  // 12. out
  final_kernel<<<BB * 3, 256, 0, stream>>>(global_bert, local_feat, out_w, out_b, out);
}